// Round 14
// baseline (1078.654 us; speedup 1.0000x reference)
//
#include <hip/hip_runtime.h>
#include <hip/hip_bf16.h>

// Elman RNN, persistent kernel v11 — no h-staging LDS (direct-global A-frags),
// double-buffered reduction LDS (ONE barrier/step), per-wave flags.
// h_t = tanh([h_{t-1} | x_t] @ [Wh|Wi]^T + (Wh_b+Wi_b)); out = h_T @ Wo^T + Wo_b
// T=128, B=512, E=256, H=1024, O=256.
//
// Geometry (r13): 32 groups x 16 rows x 8 blocks (128 cols each), 256 blocks,
// 1/CU, 8 waves; wave wv owns k-slice [wv*128,+128) -> its A-rows are
// h[R0+l15][k..k+8] = 16 contiguous bytes -> loaded DIRECTLY from global
// (per ks, a wave covers 16 rows x 64B: fully coalesced). No As LDS tile.
//
// Sync: per-wave flags. Producer block p's wave w epilogues cols [w*16,+16),
// drains ITS OWN stores (vmcnt is per-wave), posts flags[g][p][w] = t+1.
// Consumer wave wv polls producer-block wv's 8 wave flags. red[] is
// double-buffered by t&1 so no second barrier is needed.
//
// Slot-overwrite safety: block p's epilogue store at step t (slot t&1,
// overwriting h produced at t-2) happens after barrier1 of step t, which joins
// 8 waves that each polled a DISTINCT producer block's 8 wave-flags >= t.
// flag[b][u] >= t means block b's wave u passed epilogue of step t-1, which is
// after block-wide barrier1 of t-1, hence after ALL of block b's a-frag reads
// of slot (t-2)&1 drained. Union over the 8 polls = the whole group. QED.
//
// Protocol laws (measured r2..r13): asm sc0 sc1 for ALL h/flag traffic
// (local-L2-served, FETCH ~107MB); RELAXED ordering via explicit s_waitcnt
// only; sched_barrier(0) after any waitcnt whose consumers are register-only
// (rule #18); never compiler AGENT/SYSTEM atomics on the hot path.

#define T_ 128
#define B_ 512
#define E_ 256
#define H_ 1024
#define O_ 256
#define RG 16            // rows per group
#define HB (B_ * H_)     // elems per h slot (1 MB bf16)

typedef __bf16 bf16x8 __attribute__((ext_vector_type(8)));
typedef float  f32x4  __attribute__((ext_vector_type(4)));
typedef unsigned int u32x2 __attribute__((ext_vector_type(2)));
typedef unsigned int u32x4 __attribute__((ext_vector_type(4)));

static __device__ __forceinline__ unsigned short f2bf(float f) {
  unsigned u = __float_as_uint(f);
  u += 0x7fff + ((u >> 16) & 1);  // RNE
  return (unsigned short)(u >> 16);
}
static __device__ __forceinline__ unsigned pk2(float a, float b) {
  return (unsigned)f2bf(a) | ((unsigned)f2bf(b) << 16);
}
static __device__ __forceinline__ bf16x8 cvt8(const float* p) {
  float4 f0 = reinterpret_cast<const float4*>(p)[0];
  float4 f1 = reinterpret_cast<const float4*>(p)[1];
  union { u32x4 u; bf16x8 v; } r;
  r.u = (u32x4){pk2(f0.x, f0.y), pk2(f0.z, f0.w), pk2(f1.x, f1.y), pk2(f1.z, f1.w)};
  return r.v;
}
// tanh(x) = 1 - 2/(exp2(2*log2e*x)+1)
static __device__ __forceinline__ float fast_tanh(float x) {
  float e = __builtin_amdgcn_exp2f(x * 2.8853900817779268f);
  return 1.f - 2.f / (e + 1.f);
}

// Poll 8 contiguous flag words (producer block's wave flags) + rule-#18 fence.
static __device__ __forceinline__ void poll8(const unsigned* fl, unsigned tgt) {
  for (;;) {
    u32x4 a, b;
    asm volatile("global_load_dwordx4 %0, %1, off sc0 sc1" : "=v"(a) : "v"(fl) : "memory");
    asm volatile("global_load_dwordx4 %0, %1, off sc0 sc1" : "=v"(b) : "v"(fl + 4) : "memory");
    asm volatile("s_waitcnt vmcnt(0)" ::: "memory");
    __builtin_amdgcn_sched_barrier(0);  // rule #18 fence
    unsigned m = min(min(min(a.x, a.y), min(a.z, a.w)),
                     min(min(b.x, b.y), min(b.z, b.w)));
    if (m >= tgt) return;
    __builtin_amdgcn_s_sleep(1);
  }
}

// ---------------------------------------------------------------------------
__global__ void prep_kernel(const float* __restrict__ seq,
                            unsigned short* __restrict__ seq_bf,
                            unsigned* __restrict__ flags) {
  size_t idx = (size_t)blockIdx.x * blockDim.x + threadIdx.x;
  size_t stride = (size_t)gridDim.x * blockDim.x;
  const size_t nchunk = (size_t)T_ * B_ * E_ / 8;
  for (size_t i = idx; i < nchunk; i += stride) {
    union { bf16x8 v; u32x4 u; } r;
    r.v = cvt8(seq + i * 8);
    *reinterpret_cast<u32x4*>(seq_bf + i * 8) = r.u;
  }
  if (idx < 2048) {
    unsigned z = 0;
    asm volatile("global_store_dword %0, %1, off sc0 sc1"
                 :: "v"(flags + idx), "v"(z) : "memory");
  }
}

// ---------------------------------------------------------------------------
__global__ __launch_bounds__(512, 2) void rnn_fused(
    const unsigned short* __restrict__ seq_bf, const float* __restrict__ Wh_w,
    const float* __restrict__ Wh_b, const float* __restrict__ Wi_w,
    const float* __restrict__ Wi_b, const float* __restrict__ Wo_w,
    const float* __restrict__ Wo_b,
    unsigned short* __restrict__ hbuf, unsigned* __restrict__ flags,
    float* __restrict__ out) {
  __shared__ __align__(16) float red[2][8][RG][132];  // 132 KB, double-buffered

  const int tid = threadIdx.x;
  const int bid = blockIdx.x;
  // group g: 8 blocks at bids {g, g+32, ...} -> all == g (mod 8): same XCD.
  const int g = bid & 31, p = bid >> 5;   // group 0..31, producer-index 0..7
  const int R0 = g * RG, C0 = p * 128;
  const int lane = tid & 63, wv = tid >> 6;   // wv = k-slice index 0..7
  const int l15 = lane & 15, k4 = lane >> 4;  // frag coords: row=l15, kchunk+=k4

  // ---- prologue: weight fragments -> registers for all 128 steps
  bf16x8 bh[8][4];  // Wh[C0+nn*16+l15][wv*128 + (ks*4+k4)*8 ..+8]
#pragma unroll
  for (int nn = 0; nn < 8; ++nn) {
    const float* wp = Wh_w + (size_t)(C0 + nn * 16 + l15) * H_ + wv * 128 + k4 * 8;
#pragma unroll
    for (int ks = 0; ks < 4; ++ks) bh[nn][ks] = cvt8(wp + ks * 32);
  }
  bf16x8 wif[8];    // Wi[C0+nn*16+l15][wv*32 + k4*8 ..+8]
#pragma unroll
  for (int nn = 0; nn < 8; ++nn)
    wif[nn] = cvt8(Wi_w + (size_t)(C0 + nn * 16 + l15) * E_ + wv * 32 + k4 * 8);

  // per-wave epilogue mapping: wave wv owns cols [wv*16,+16); lane -> (er, 4 cols)
  const int er = lane >> 2;                 // row 0..15
  const int ecl = wv * 16 + (lane & 3) * 4; // local col 0..127
  f32x4 bias4;
  {
    f32x4 b1 = *reinterpret_cast<const f32x4*>(Wh_b + C0 + ecl);
    f32x4 b2 = *reinterpret_cast<const f32x4*>(Wi_b + C0 + ecl);
    bias4 = b1 + b2;
  }
  // flags: [group][producer p][wave w] at g*64 + p*8 + w
  const unsigned* wvfl = flags + g * 64 + wv * 8;  // producer block wv's 8 wave flags
  unsigned* myfl = flags + g * 64 + p * 8 + wv;    // this block, this wave
  const size_t hoff_b = ((size_t)(R0 + er) * H_ + C0 + ecl) * 2;  // bytes
  // a-frag base (elems within a slot): row R0+l15, col wv*128 + k4*8
  const size_t afr_e = (size_t)(R0 + l15) * H_ + wv * 128 + k4 * 8;

  for (int t = 0; t < T_; ++t) {
    f32x4 acc[8];
#pragma unroll
    for (int nn = 0; nn < 8; ++nn) acc[nn] = (f32x4){0.f, 0.f, 0.f, 0.f};
    // ---- x a-frag (no h dependence; in flight during the poll)
    bf16x8 xa = *reinterpret_cast<const bf16x8*>(
        seq_bf + ((size_t)t * B_ + R0 + l15) * E_ + wv * 32 + k4 * 8);
    u32x4 a0, a1, a2, a3;
    if (t > 0) {
      poll8(wvfl, (unsigned)t);  // producer block wv finished step t-1 (all waves)
      // ---- direct-global A-frags: 4 x 16B per lane, 16 rows x 64B per wave/ks
      const unsigned char* ab =
          (const unsigned char*)(hbuf + (size_t)((t - 1) & 1) * HB + afr_e);
      asm volatile("global_load_dwordx4 %0, %1, off sc0 sc1"
                   : "=v"(a0) : "v"(ab) : "memory");
      asm volatile("global_load_dwordx4 %0, %1, off sc0 sc1"
                   : "=v"(a1) : "v"(ab + 64) : "memory");
      asm volatile("global_load_dwordx4 %0, %1, off sc0 sc1"
                   : "=v"(a2) : "v"(ab + 128) : "memory");
      asm volatile("global_load_dwordx4 %0, %1, off sc0 sc1"
                   : "=v"(a3) : "v"(ab + 192) : "memory");
    }
    // ---- x-part: 8 MFMAs overlap the a-frag loads in flight
#pragma unroll
    for (int nn = 0; nn < 8; ++nn)
      acc[nn] = __builtin_amdgcn_mfma_f32_16x16x32_bf16(xa, wif[nn], acc[nn], 0, 0, 0);
    if (t > 0) {
      asm volatile("s_waitcnt vmcnt(0)" ::: "memory");
      __builtin_amdgcn_sched_barrier(0);  // rule #18: a-frags feed MFMA directly
      union { u32x4 u; bf16x8 v; } af;
#define RNN_HMF(KS, AV)                                                          \
      af.u = AV;                                                                 \
      _Pragma("unroll")                                                          \
      for (int nn = 0; nn < 8; ++nn)                                             \
        acc[nn] = __builtin_amdgcn_mfma_f32_16x16x32_bf16(af.v, bh[nn][KS],      \
                                                          acc[nn], 0, 0, 0);
      RNN_HMF(0, a0) RNN_HMF(1, a1) RNN_HMF(2, a2) RNN_HMF(3, a3)
#undef RNN_HMF
    }
    // ---- k-split partials -> red[t&1][wv] (C layout: col=l15, row=k4*4+r)
    {
      float* rb = &red[t & 1][wv][0][0];
#pragma unroll
      for (int nn = 0; nn < 8; ++nn)
#pragma unroll
        for (int r = 0; r < 4; ++r)
          rb[(k4 * 4 + r) * 132 + nn * 16 + l15] = acc[nn][r];
    }
    __syncthreads();  // the ONLY barrier per step
    // ---- per-wave epilogue: reduce 8 slices, bias, tanh, 8B store, own flag
    {
      const float* rb = &red[t & 1][0][0][0];
      f32x4 v = *reinterpret_cast<const f32x4*>(rb + er * 132 + ecl);
#pragma unroll
      for (int s = 1; s < 8; ++s)
        v += *reinterpret_cast<const f32x4*>(rb + (s * RG + er) * 132 + ecl);
      v += bias4;
      u32x2 pv = {pk2(fast_tanh(v[0]), fast_tanh(v[1])),
                  pk2(fast_tanh(v[2]), fast_tanh(v[3]))};
      const unsigned char* dst =
          (const unsigned char*)hbuf + (size_t)(t & 1) * (HB * 2) + hoff_b;
      asm volatile("global_store_dwordx2 %0, %1, off sc0 sc1"
                   :: "v"(dst), "v"(pv) : "memory");
    }
    asm volatile("s_waitcnt vmcnt(0)" ::: "memory");  // own stores acked
    if (lane == 0) {
      unsigned fv = (unsigned)(t + 1);
      asm volatile("global_store_dword %0, %1, off sc0 sc1"
                   :: "v"(myfl), "v"(fv) : "memory");
    }
  }

  // ---- final GEMM: out = h_T @ Wo^T + Wo_b (blocks p<2 cover 512x256, fp32)
  if (p >= 2) return;
  {
    poll8(wvfl, (unsigned)T_);
    const unsigned char* ab =
        (const unsigned char*)(hbuf + (size_t)((T_ - 1) & 1) * HB + afr_e);
    u32x4 a0, a1, a2, a3;
    asm volatile("global_load_dwordx4 %0, %1, off sc0 sc1" : "=v"(a0) : "v"(ab) : "memory");
    asm volatile("global_load_dwordx4 %0, %1, off sc0 sc1" : "=v"(a1) : "v"(ab + 64) : "memory");
    asm volatile("global_load_dwordx4 %0, %1, off sc0 sc1" : "=v"(a2) : "v"(ab + 128) : "memory");
    asm volatile("global_load_dwordx4 %0, %1, off sc0 sc1" : "=v"(a3) : "v"(ab + 192) : "memory");
    asm volatile("s_waitcnt vmcnt(0)" ::: "memory");
    __builtin_amdgcn_sched_barrier(0);
    f32x4 acc[8];
#pragma unroll
    for (int nn = 0; nn < 8; ++nn) acc[nn] = (f32x4){0.f, 0.f, 0.f, 0.f};
    union { u32x4 u; bf16x8 v; } af;
#define RNN_OMF(KS, AV)                                                          \
    af.u = AV;                                                                   \
    _Pragma("unroll")                                                            \
    for (int nn = 0; nn < 8; ++nn) {                                             \
      bf16x8 b = cvt8(Wo_w + (size_t)(C0 + nn * 16 + l15) * H_ +                 \
                      wv * 128 + (KS) * 32 + k4 * 8);                            \
      acc[nn] = __builtin_amdgcn_mfma_f32_16x16x32_bf16(af.v, b, acc[nn], 0, 0, 0); \
    }
    RNN_OMF(0, a0) RNN_OMF(1, a1) RNN_OMF(2, a2) RNN_OMF(3, a3)
#undef RNN_OMF
    {
      float* rb = &red[0][wv][0][0];
#pragma unroll
      for (int nn = 0; nn < 8; ++nn)
#pragma unroll
        for (int r = 0; r < 4; ++r)
          rb[(k4 * 4 + r) * 132 + nn * 16 + l15] = acc[nn][r];
    }
    __syncthreads();
    {
      const float* rb = &red[0][0][0][0];
      f32x4 v = *reinterpret_cast<const f32x4*>(rb + er * 132 + ecl);
#pragma unroll
      for (int s = 1; s < 8; ++s)
        v += *reinterpret_cast<const f32x4*>(rb + (s * RG + er) * 132 + ecl);
      v += *reinterpret_cast<const f32x4*>(Wo_b + C0 + ecl);
      *reinterpret_cast<f32x4*>(out + (size_t)(R0 + er) * O_ + C0 + ecl) = v;
    }
  }
}

// ---------------------------------------------------------------------------
extern "C" void kernel_launch(void* const* d_in, const int* in_sizes, int n_in,
                              void* d_out, int out_size, void* d_ws, size_t ws_size,
                              hipStream_t stream) {
  const float* seq  = (const float*)d_in[0];
  const float* Wh_w = (const float*)d_in[1];
  const float* Wh_b = (const float*)d_in[2];
  const float* Wi_w = (const float*)d_in[3];
  const float* Wi_b = (const float*)d_in[4];
  const float* Wo_w = (const float*)d_in[5];
  const float* Wo_b = (const float*)d_in[6];

  char* ws = (char*)d_ws;
  unsigned short* hbuf   = (unsigned short*)ws; ws += (size_t)2 * HB * 2;  // 2 MB
  unsigned*       flags  = (unsigned*)ws;       ws += 8192;                // 32 x 256B
  unsigned short* seq_bf = (unsigned short*)ws;                            // 32 MB

  prep_kernel<<<2048, 256, 0, stream>>>(seq, seq_bf, flags);
  rnn_fused<<<256, 512, 0, stream>>>(seq_bf, Wh_w, Wh_b, Wi_w, Wi_b, Wo_w, Wo_b,
                                     hbuf, flags, (float*)d_out);
}

// Round 15
// 426.315 us; speedup vs baseline: 2.5302x; 2.5302x over previous
//
#include <hip/hip_runtime.h>
#include <hip/hip_bf16.h>

// Elman RNN, persistent kernel v12 = r13 (453us best) + ONE change:
// direct-global A-frags in MFMA layout (removes the As LDS round-trip).
// h_t = tanh([h_{t-1} | x_t] @ [Wh|Wi]^T + (Wh_b+Wi_b)); out = h_T @ Wo^T + Wo_b
// T=128, B=512, E=256, H=1024, O=256.
//
// Geometry (r13): 32 groups x 16 rows x 8 blocks (128 cols each), 256 blocks,
// 1/CU, 8 waves; wave wv owns k-slice [wv*128,+128); sync degree 1 (wave wv
// polls producer-block wv's single block-flag).
//
// Measured laws:
//  r9/r10/r11: 1 block/CU lockstep beats all added-concurrency variants.
//  r14: BARRIERS ARE SKEW RESETS — per-wave flags + no barrier => wave skew
//       compounds across the 128-step chain (453->1079us). Keep block flag +
//       both barriers EXACTLY as r13.
//  r2: RELEASE/agent atomics -> L2 writeback flush. Never.
//  r4/5/9/13: asm sc0 sc1 loads/stores: h+flags local-L2-served, FETCH ~107MB.
//  r6: asm load + waitcnt + register-only consumer needs sched_barrier(0).
//  r7/r8: compiler AGENT/SYSTEM atomic polls -> MALL/HBM storms. Never.
//
// Direct A-frag: for MFMA ks, lane(l15,k4) needs h[R0+l15][wv*128+ks*32+k4*8
// ..+8] = 16B at byte l15*2048 + wv*256 + ks*64 + k4*16. Per load instruction
// the wave covers 16 rows x 64B contiguous: fully coalesced. The old LDS
// stage existed only to shuffle stage-layout->frag-layout; loading directly
// in frag layout makes it pure overhead (write+lgkm+readback ~300-400cy/step).
//
// Slot-overwrite safety (r13 proof, loads now global): block p's epilogue
// store at step t (slot t&1, overwriting h of t-2) is after barrier1(t), which
// joins 8 waves that each polled a DISTINCT producer flag >= t. flag[j] >= t
// means block j passed barrier2(t-1), hence all its A-frag reads of slot
// (t-2)&1 were vmcnt-drained before its h-MFMAs at t-1. Union = whole group.

#define T_ 128
#define B_ 512
#define E_ 256
#define H_ 1024
#define O_ 256
#define RG 16            // rows per group
#define HB (B_ * H_)     // elems per h slot (1 MB bf16)

typedef __bf16 bf16x8 __attribute__((ext_vector_type(8)));
typedef float  f32x4  __attribute__((ext_vector_type(4)));
typedef unsigned int u32x2 __attribute__((ext_vector_type(2)));
typedef unsigned int u32x4 __attribute__((ext_vector_type(4)));

static __device__ __forceinline__ unsigned short f2bf(float f) {
  unsigned u = __float_as_uint(f);
  u += 0x7fff + ((u >> 16) & 1);  // RNE
  return (unsigned short)(u >> 16);
}
static __device__ __forceinline__ unsigned pk2(float a, float b) {
  return (unsigned)f2bf(a) | ((unsigned)f2bf(b) << 16);
}
static __device__ __forceinline__ bf16x8 cvt8(const float* p) {
  float4 f0 = reinterpret_cast<const float4*>(p)[0];
  float4 f1 = reinterpret_cast<const float4*>(p)[1];
  union { u32x4 u; bf16x8 v; } r;
  r.u = (u32x4){pk2(f0.x, f0.y), pk2(f0.z, f0.w), pk2(f1.x, f1.y), pk2(f1.z, f1.w)};
  return r.v;
}
// tanh(x) = 1 - 2/(exp2(2*log2e*x)+1)
static __device__ __forceinline__ float fast_tanh(float x) {
  float e = __builtin_amdgcn_exp2f(x * 2.8853900817779268f);
  return 1.f - 2.f / (e + 1.f);
}

// Poll ONE flag word (this wave's single producer block) + rule-#18 fence.
static __device__ __forceinline__ void poll1(const unsigned* fl, unsigned tgt) {
  for (;;) {
    unsigned a;
    asm volatile("global_load_dword %0, %1, off sc0 sc1"
                 : "=v"(a) : "v"(fl) : "memory");
    asm volatile("s_waitcnt vmcnt(0)" ::: "memory");
    __builtin_amdgcn_sched_barrier(0);  // rule #18 fence
    if (a >= tgt) return;
    __builtin_amdgcn_s_sleep(1);
  }
}

// ---------------------------------------------------------------------------
__global__ void prep_kernel(const float* __restrict__ seq,
                            unsigned short* __restrict__ seq_bf,
                            unsigned* __restrict__ flags) {
  size_t idx = (size_t)blockIdx.x * blockDim.x + threadIdx.x;
  size_t stride = (size_t)gridDim.x * blockDim.x;
  const size_t nchunk = (size_t)T_ * B_ * E_ / 8;
  for (size_t i = idx; i < nchunk; i += stride) {
    union { bf16x8 v; u32x4 u; } r;
    r.v = cvt8(seq + i * 8);
    *reinterpret_cast<u32x4*>(seq_bf + i * 8) = r.u;
  }
  if (idx < 1024) {
    unsigned z = 0;
    asm volatile("global_store_dword %0, %1, off sc0 sc1"
                 :: "v"(flags + idx), "v"(z) : "memory");
  }
}

// ---------------------------------------------------------------------------
__global__ __launch_bounds__(512, 2) void rnn_fused(
    const unsigned short* __restrict__ seq_bf, const float* __restrict__ Wh_w,
    const float* __restrict__ Wh_b, const float* __restrict__ Wi_w,
    const float* __restrict__ Wi_b, const float* __restrict__ Wo_w,
    const float* __restrict__ Wo_b,
    unsigned short* __restrict__ hbuf, unsigned* __restrict__ flags,
    float* __restrict__ out) {
  __shared__ __align__(16) float red[8][RG][132];  // 67.6 KB k-split partials

  const int tid = threadIdx.x;
  const int bid = blockIdx.x;
  // group g: 8 blocks at bids {g, g+32, ...} -> all == g (mod 8): same XCD.
  const int g = bid & 31, p = bid >> 5;   // group 0..31, producer-index 0..7
  const int R0 = g * RG, C0 = p * 128;
  const int lane = tid & 63, wv = tid >> 6;   // wv = k-slice index 0..7
  const int l15 = lane & 15, k4 = lane >> 4;  // frag coords: row=l15, kchunk+=k4

  // ---- prologue: weight fragments -> registers for all 128 steps
  bf16x8 bh[8][4];  // Wh[C0+nn*16+l15][wv*128 + (ks*4+k4)*8 ..+8]
#pragma unroll
  for (int nn = 0; nn < 8; ++nn) {
    const float* wp = Wh_w + (size_t)(C0 + nn * 16 + l15) * H_ + wv * 128 + k4 * 8;
#pragma unroll
    for (int ks = 0; ks < 4; ++ks) bh[nn][ks] = cvt8(wp + ks * 32);
  }
  bf16x8 wif[8];    // Wi[C0+nn*16+l15][wv*32 + k4*8 ..+8]
#pragma unroll
  for (int nn = 0; nn < 8; ++nn)
    wif[nn] = cvt8(Wi_w + (size_t)(C0 + nn * 16 + l15) * E_ + wv * 32 + k4 * 8);

  // epilogue mapping (r13): thread -> (erow, cols ec..ec+3)
  const int erow = tid >> 5, ec = (tid & 31) * 4;
  f32x4 bias4;
  {
    f32x4 b1 = *reinterpret_cast<const f32x4*>(Wh_b + C0 + ec);
    f32x4 b2 = *reinterpret_cast<const f32x4*>(Wi_b + C0 + ec);
    bias4 = b1 + b2;
  }
  const unsigned* wvfl = flags + g * 32 + wv;  // this wave's single producer
  unsigned* myfl = flags + g * 32 + p;
  const size_t hoff_b = ((size_t)(R0 + erow) * H_ + C0 + ec) * 2;  // bytes
  // A-frag base bytes within a slot: row R0+l15, col wv*128 + k4*8
  const size_t afr_b = (size_t)(R0 + l15) * 2048 + wv * 256 + k4 * 16;

  for (int t = 0; t < T_; ++t) {
    f32x4 acc[8];
#pragma unroll
    for (int nn = 0; nn < 8; ++nn) acc[nn] = (f32x4){0.f, 0.f, 0.f, 0.f};
    // ---- x a-frag (no h dependence)
    bf16x8 xa = *reinterpret_cast<const bf16x8*>(
        seq_bf + ((size_t)t * B_ + R0 + l15) * E_ + wv * 32 + k4 * 8);
    // ---- first half of x-part: useful work absorbing producer lag
#pragma unroll
    for (int nn = 0; nn < 4; ++nn)
      acc[nn] = __builtin_amdgcn_mfma_f32_16x16x32_bf16(xa, wif[nn], acc[nn], 0, 0, 0);
    u32x4 a0, a1, a2, a3;
    if (t > 0) {
      poll1(wvfl, (unsigned)t);  // ONE producer: block wv of this group
      // ---- direct-global A-frags in MFMA layout (16 rows x 64B per instr)
      const unsigned char* ab =
          (const unsigned char*)hbuf + (size_t)((t - 1) & 1) * (HB * 2) + afr_b;
      asm volatile("global_load_dwordx4 %0, %1, off sc0 sc1"
                   : "=v"(a0) : "v"(ab) : "memory");
      asm volatile("global_load_dwordx4 %0, %1, off sc0 sc1"
                   : "=v"(a1) : "v"(ab + 64) : "memory");
      asm volatile("global_load_dwordx4 %0, %1, off sc0 sc1"
                   : "=v"(a2) : "v"(ab + 128) : "memory");
      asm volatile("global_load_dwordx4 %0, %1, off sc0 sc1"
                   : "=v"(a3) : "v"(ab + 192) : "memory");
    }
    // ---- second half of x-part overlaps the A-frag loads in flight
#pragma unroll
    for (int nn = 4; nn < 8; ++nn)
      acc[nn] = __builtin_amdgcn_mfma_f32_16x16x32_bf16(xa, wif[nn], acc[nn], 0, 0, 0);
    if (t > 0) {
      asm volatile("s_waitcnt vmcnt(0)" ::: "memory");
      __builtin_amdgcn_sched_barrier(0);  // rule #18: a-frags feed MFMA directly
      union { u32x4 u; bf16x8 v; } af;
#define RNN_HMF(KS, AV)                                                          \
      af.u = AV;                                                                 \
      _Pragma("unroll")                                                          \
      for (int nn = 0; nn < 8; ++nn)                                             \
        acc[nn] = __builtin_amdgcn_mfma_f32_16x16x32_bf16(af.v, bh[nn][KS],      \
                                                          acc[nn], 0, 0, 0);
      RNN_HMF(0, a0) RNN_HMF(1, a1) RNN_HMF(2, a2) RNN_HMF(3, a3)
#undef RNN_HMF
    }
    // ---- k-split partials (C layout: col=l15, row=k4*4+r)
#pragma unroll
    for (int nn = 0; nn < 8; ++nn)
#pragma unroll
      for (int r = 0; r < 4; ++r)
        red[wv][k4 * 4 + r][nn * 16 + l15] = acc[nn][r];
    __syncthreads();  // barrier 1: partials in
    // ---- distributed epilogue: 4 cols/thread, 8-source reduce, tanh, 8B store
    {
      f32x4 v = *reinterpret_cast<const f32x4*>(&red[0][erow][ec]);
#pragma unroll
      for (int s = 1; s < 8; ++s)
        v += *reinterpret_cast<const f32x4*>(&red[s][erow][ec]);
      v += bias4;
      u32x2 pv = {pk2(fast_tanh(v[0]), fast_tanh(v[1])),
                  pk2(fast_tanh(v[2]), fast_tanh(v[3]))};
      const unsigned char* dst =
          (const unsigned char*)hbuf + (size_t)(t & 1) * (HB * 2) + hoff_b;
      asm volatile("global_store_dwordx2 %0, %1, off sc0 sc1"
                   :: "v"(dst), "v"(pv) : "memory");
    }
    asm volatile("s_waitcnt vmcnt(0)" ::: "memory");  // h stores acked
    __syncthreads();  // barrier 2: all stores drained before the flag
    if (tid == 0) {
      unsigned fv = (unsigned)(t + 1);
      asm volatile("global_store_dword %0, %1, off sc0 sc1"
                   :: "v"(myfl), "v"(fv) : "memory");
    }
  }

  // ---- final GEMM: out = h_T @ Wo^T + Wo_b (blocks p<2 cover 512x256, fp32)
  if (p >= 2) return;
  {
    poll1(wvfl, (unsigned)T_);
    const unsigned char* ab =
        (const unsigned char*)hbuf + (size_t)((T_ - 1) & 1) * (HB * 2) + afr_b;
    u32x4 a0, a1, a2, a3;
    asm volatile("global_load_dwordx4 %0, %1, off sc0 sc1" : "=v"(a0) : "v"(ab) : "memory");
    asm volatile("global_load_dwordx4 %0, %1, off sc0 sc1" : "=v"(a1) : "v"(ab + 64) : "memory");
    asm volatile("global_load_dwordx4 %0, %1, off sc0 sc1" : "=v"(a2) : "v"(ab + 128) : "memory");
    asm volatile("global_load_dwordx4 %0, %1, off sc0 sc1" : "=v"(a3) : "v"(ab + 192) : "memory");
    asm volatile("s_waitcnt vmcnt(0)" ::: "memory");
    __builtin_amdgcn_sched_barrier(0);
    f32x4 acc[8];
#pragma unroll
    for (int nn = 0; nn < 8; ++nn) acc[nn] = (f32x4){0.f, 0.f, 0.f, 0.f};
    union { u32x4 u; bf16x8 v; } af;
#define RNN_OMF(KS, AV)                                                          \
    af.u = AV;                                                                   \
    _Pragma("unroll")                                                            \
    for (int nn = 0; nn < 8; ++nn) {                                             \
      bf16x8 b = cvt8(Wo_w + (size_t)(C0 + nn * 16 + l15) * H_ +                 \
                      wv * 128 + (KS) * 32 + k4 * 8);                            \
      acc[nn] = __builtin_amdgcn_mfma_f32_16x16x32_bf16(af.v, b, acc[nn], 0, 0, 0); \
    }
    RNN_OMF(0, a0) RNN_OMF(1, a1) RNN_OMF(2, a2) RNN_OMF(3, a3)
#undef RNN_OMF
#pragma unroll
    for (int nn = 0; nn < 8; ++nn)
#pragma unroll
      for (int r = 0; r < 4; ++r)
        red[wv][k4 * 4 + r][nn * 16 + l15] = acc[nn][r];
    __syncthreads();
    {
      f32x4 v = *reinterpret_cast<const f32x4*>(&red[0][erow][ec]);
#pragma unroll
      for (int s = 1; s < 8; ++s)
        v += *reinterpret_cast<const f32x4*>(&red[s][erow][ec]);
      v += *reinterpret_cast<const f32x4*>(Wo_b + C0 + ec);
      *reinterpret_cast<f32x4*>(out + (size_t)(R0 + erow) * O_ + C0 + ec) = v;
    }
  }
}

// ---------------------------------------------------------------------------
extern "C" void kernel_launch(void* const* d_in, const int* in_sizes, int n_in,
                              void* d_out, int out_size, void* d_ws, size_t ws_size,
                              hipStream_t stream) {
  const float* seq  = (const float*)d_in[0];
  const float* Wh_w = (const float*)d_in[1];
  const float* Wh_b = (const float*)d_in[2];
  const float* Wi_w = (const float*)d_in[3];
  const float* Wi_b = (const float*)d_in[4];
  const float* Wo_w = (const float*)d_in[5];
  const float* Wo_b = (const float*)d_in[6];

  char* ws = (char*)d_ws;
  unsigned short* hbuf   = (unsigned short*)ws; ws += (size_t)2 * HB * 2;  // 2 MB
  unsigned*       flags  = (unsigned*)ws;       ws += 4096;                // 32 x 128B
  unsigned short* seq_bf = (unsigned short*)ws;                            // 32 MB

  prep_kernel<<<2048, 256, 0, stream>>>(seq, seq_bf, flags);
  rnn_fused<<<256, 512, 0, stream>>>(seq_bf, Wh_w, Wh_b, Wi_w, Wi_b, Wo_w, Wo_b,
                                     hbuf, flags, (float*)d_out);
}

// Round 16
// 405.818 us; speedup vs baseline: 2.6580x; 1.0505x over previous
//
#include <hip/hip_runtime.h>
#include <hip/hip_bf16.h>

// Elman RNN, persistent kernel v13 = r15 (426us best) + two latency fixes:
//  (1) per-flag 128B lines (kills flag false-sharing: 8 stores + 64 polling
//      waves previously hammered ONE L2 line per group per step),
//  (2) poll-first schedule + counted vmcnt drains (a-frag loads overlap all
//      8 x-MFMAs; h-MFMA batches gated by vmcnt(3/2/1/0), not one vmcnt(0)).
// h_t = tanh([h_{t-1} | x_t] @ [Wh|Wi]^T + (Wh_b+Wi_b)); out = h_T @ Wo^T + Wo_b
// T=128, B=512, E=256, H=1024, O=256.
//
// Geometry (r13/r15): 32 groups x 16 rows x 8 blocks (128 cols), 256 blocks,
// 1/CU, 8 waves; wave wv owns k-slice [wv*128,+128); sync degree 1 (wave wv
// polls producer-block wv's flag). Register-bound: bh[8][4]=128 VGPR/thread
// is the max -> 128 cols/block is forced -> groups of 8.
//
// Measured laws:
//  r9/r10/r11: 1 block/CU lockstep beats all added-concurrency variants.
//  r14: barriers are skew resets; keep block flag + both barriers (r13 form).
//  r2: RELEASE/agent atomics -> L2 writeback flush. Never.
//  r4/5/9/13/15: asm sc0 sc1 for h+flag traffic; local-L2-served.
//  r6: asm load + waitcnt + register-only consumer needs sched_barrier(0).
//  r7/r8: compiler AGENT/SYSTEM atomic polls -> MALL/HBM storms. Never.
//  r15: direct-global A-frags in MFMA layout: bank conflicts 0, -27us.
//
// xa is an ASM load so the compiler can't emit its own vmcnt(0) for it after
// the a-frag issues (it can't count asm loads; its conservative drain would
// serialize the overlap). poll1's internal vmcnt(0) doubles as xa's drain.

#define T_ 128
#define B_ 512
#define E_ 256
#define H_ 1024
#define O_ 256
#define RG 16            // rows per group
#define HB (B_ * H_)     // elems per h slot (1 MB bf16)

typedef __bf16 bf16x8 __attribute__((ext_vector_type(8)));
typedef float  f32x4  __attribute__((ext_vector_type(4)));
typedef unsigned int u32x2 __attribute__((ext_vector_type(2)));
typedef unsigned int u32x4 __attribute__((ext_vector_type(4)));

static __device__ __forceinline__ unsigned short f2bf(float f) {
  unsigned u = __float_as_uint(f);
  u += 0x7fff + ((u >> 16) & 1);  // RNE
  return (unsigned short)(u >> 16);
}
static __device__ __forceinline__ unsigned pk2(float a, float b) {
  return (unsigned)f2bf(a) | ((unsigned)f2bf(b) << 16);
}
static __device__ __forceinline__ bf16x8 cvt8(const float* p) {
  float4 f0 = reinterpret_cast<const float4*>(p)[0];
  float4 f1 = reinterpret_cast<const float4*>(p)[1];
  union { u32x4 u; bf16x8 v; } r;
  r.u = (u32x4){pk2(f0.x, f0.y), pk2(f0.z, f0.w), pk2(f1.x, f1.y), pk2(f1.z, f1.w)};
  return r.v;
}
// tanh(x) = 1 - 2/(exp2(2*log2e*x)+1)
static __device__ __forceinline__ float fast_tanh(float x) {
  float e = __builtin_amdgcn_exp2f(x * 2.8853900817779268f);
  return 1.f - 2.f / (e + 1.f);
}

// Poll ONE flag word (own 128B line) + rule-#18 fence. Ends with vmcnt(0):
// everything issued before the poll (e.g. xa) is drained on return.
static __device__ __forceinline__ void poll1(const unsigned* fl, unsigned tgt) {
  for (;;) {
    unsigned a;
    asm volatile("global_load_dword %0, %1, off sc0 sc1"
                 : "=v"(a) : "v"(fl) : "memory");
    asm volatile("s_waitcnt vmcnt(0)" ::: "memory");
    __builtin_amdgcn_sched_barrier(0);  // rule #18 fence
    if (a >= tgt) return;
    __builtin_amdgcn_s_sleep(1);
  }
}

// ---------------------------------------------------------------------------
__global__ void prep_kernel(const float* __restrict__ seq,
                            unsigned short* __restrict__ seq_bf,
                            unsigned* __restrict__ flags) {
  size_t idx = (size_t)blockIdx.x * blockDim.x + threadIdx.x;
  size_t stride = (size_t)gridDim.x * blockDim.x;
  const size_t nchunk = (size_t)T_ * B_ * E_ / 8;
  for (size_t i = idx; i < nchunk; i += stride) {
    union { bf16x8 v; u32x4 u; } r;
    r.v = cvt8(seq + i * 8);
    *reinterpret_cast<u32x4*>(seq_bf + i * 8) = r.u;
  }
  if (idx < 8192) {  // 32 groups x 8 producers x 32-word (128B) lines
    unsigned z = 0;
    asm volatile("global_store_dword %0, %1, off sc0 sc1"
                 :: "v"(flags + idx), "v"(z) : "memory");
  }
}

// ---------------------------------------------------------------------------
__global__ __launch_bounds__(512, 2) void rnn_fused(
    const unsigned short* __restrict__ seq_bf, const float* __restrict__ Wh_w,
    const float* __restrict__ Wh_b, const float* __restrict__ Wi_w,
    const float* __restrict__ Wi_b, const float* __restrict__ Wo_w,
    const float* __restrict__ Wo_b,
    unsigned short* __restrict__ hbuf, unsigned* __restrict__ flags,
    float* __restrict__ out) {
  __shared__ __align__(16) float red[8][RG][132];  // 67.6 KB k-split partials

  const int tid = threadIdx.x;
  const int bid = blockIdx.x;
  // group g: 8 blocks at bids {g, g+32, ...} -> all == g (mod 8): same XCD.
  const int g = bid & 31, p = bid >> 5;   // group 0..31, producer-index 0..7
  const int R0 = g * RG, C0 = p * 128;
  const int lane = tid & 63, wv = tid >> 6;   // wv = k-slice index 0..7
  const int l15 = lane & 15, k4 = lane >> 4;  // frag coords: row=l15, kchunk+=k4

  // ---- prologue: weight fragments -> registers for all 128 steps
  bf16x8 bh[8][4];  // Wh[C0+nn*16+l15][wv*128 + (ks*4+k4)*8 ..+8]
#pragma unroll
  for (int nn = 0; nn < 8; ++nn) {
    const float* wp = Wh_w + (size_t)(C0 + nn * 16 + l15) * H_ + wv * 128 + k4 * 8;
#pragma unroll
    for (int ks = 0; ks < 4; ++ks) bh[nn][ks] = cvt8(wp + ks * 32);
  }
  bf16x8 wif[8];    // Wi[C0+nn*16+l15][wv*32 + k4*8 ..+8]
#pragma unroll
  for (int nn = 0; nn < 8; ++nn)
    wif[nn] = cvt8(Wi_w + (size_t)(C0 + nn * 16 + l15) * E_ + wv * 32 + k4 * 8);

  // epilogue mapping (r13): thread -> (erow, cols ec..ec+3)
  const int erow = tid >> 5, ec = (tid & 31) * 4;
  f32x4 bias4;
  {
    f32x4 b1 = *reinterpret_cast<const f32x4*>(Wh_b + C0 + ec);
    f32x4 b2 = *reinterpret_cast<const f32x4*>(Wi_b + C0 + ec);
    bias4 = b1 + b2;
  }
  // flags: one 128B line per (group, producer): word index g*256 + p*32
  const unsigned* wvfl = flags + g * 256 + wv * 32;  // this wave's producer line
  unsigned* myfl = flags + g * 256 + p * 32;
  const size_t hoff_b = ((size_t)(R0 + erow) * H_ + C0 + ec) * 2;  // bytes
  // A-frag base bytes within a slot: row R0+l15, col wv*128 + k4*8
  const size_t afr_b = (size_t)(R0 + l15) * 2048 + wv * 256 + k4 * 16;

  for (int t = 0; t < T_; ++t) {
    f32x4 acc[8];
#pragma unroll
    for (int nn = 0; nn < 8; ++nn) acc[nn] = (f32x4){0.f, 0.f, 0.f, 0.f};
    // ---- issue xa as ASM load (drained by poll1's vmcnt(0), not compiler's)
    union { u32x4 u; bf16x8 v; } xa;
    {
      const unsigned char* xp = (const unsigned char*)seq_bf +
          (((size_t)t * B_ + R0 + l15) * E_ + wv * 32 + k4 * 8) * 2;
      asm volatile("global_load_dwordx4 %0, %1, off"
                   : "=v"(xa.u) : "v"(xp) : "memory");
    }
    u32x4 a0, a1, a2, a3;
    if (t > 0) {
      poll1(wvfl, (unsigned)t);  // ends vmcnt(0)+fence: xa now in-register too
      // ---- issue direct-global A-frags (16 rows x 64B per instr, coalesced)
      const unsigned char* ab =
          (const unsigned char*)hbuf + (size_t)((t - 1) & 1) * (HB * 2) + afr_b;
      asm volatile("global_load_dwordx4 %0, %1, off sc0 sc1"
                   : "=v"(a0) : "v"(ab) : "memory");
      asm volatile("global_load_dwordx4 %0, %1, off sc0 sc1"
                   : "=v"(a1) : "v"(ab + 64) : "memory");
      asm volatile("global_load_dwordx4 %0, %1, off sc0 sc1"
                   : "=v"(a2) : "v"(ab + 128) : "memory");
      asm volatile("global_load_dwordx4 %0, %1, off sc0 sc1"
                   : "=v"(a3) : "v"(ab + 192) : "memory");
    } else {
      asm volatile("s_waitcnt vmcnt(0)" ::: "memory");  // xa ready (t==0 path)
      __builtin_amdgcn_sched_barrier(0);
    }
    // ---- all 8 x-MFMAs overlap the a-frag loads in flight
#pragma unroll
    for (int nn = 0; nn < 8; ++nn)
      acc[nn] = __builtin_amdgcn_mfma_f32_16x16x32_bf16(xa.v, wif[nn], acc[nn], 0, 0, 0);
    if (t > 0) {
      // ---- counted drains: consume each a-frag as it lands (T4 pattern)
      union { u32x4 u; bf16x8 v; } af;
#define RNN_HMF(N, KS, AV)                                                       \
      asm volatile("s_waitcnt vmcnt(" #N ")" ::: "memory");                      \
      __builtin_amdgcn_sched_barrier(0);  /* rule #18 */                         \
      af.u = AV;                                                                 \
      _Pragma("unroll")                                                          \
      for (int nn = 0; nn < 8; ++nn)                                             \
        acc[nn] = __builtin_amdgcn_mfma_f32_16x16x32_bf16(af.v, bh[nn][KS],      \
                                                          acc[nn], 0, 0, 0);
      RNN_HMF(3, 0, a0) RNN_HMF(2, 1, a1) RNN_HMF(1, 2, a2) RNN_HMF(0, 3, a3)
#undef RNN_HMF
    }
    // ---- k-split partials (C layout: col=l15, row=k4*4+r)
#pragma unroll
    for (int nn = 0; nn < 8; ++nn)
#pragma unroll
      for (int r = 0; r < 4; ++r)
        red[wv][k4 * 4 + r][nn * 16 + l15] = acc[nn][r];
    __syncthreads();  // barrier 1: partials in
    // ---- distributed epilogue: 4 cols/thread, 8-source reduce, tanh, 8B store
    {
      f32x4 v = *reinterpret_cast<const f32x4*>(&red[0][erow][ec]);
#pragma unroll
      for (int s = 1; s < 8; ++s)
        v += *reinterpret_cast<const f32x4*>(&red[s][erow][ec]);
      v += bias4;
      u32x2 pv = {pk2(fast_tanh(v[0]), fast_tanh(v[1])),
                  pk2(fast_tanh(v[2]), fast_tanh(v[3]))};
      const unsigned char* dst =
          (const unsigned char*)hbuf + (size_t)(t & 1) * (HB * 2) + hoff_b;
      asm volatile("global_store_dwordx2 %0, %1, off sc0 sc1"
                   :: "v"(dst), "v"(pv) : "memory");
    }
    asm volatile("s_waitcnt vmcnt(0)" ::: "memory");  // h stores acked
    __syncthreads();  // barrier 2: all stores drained before the flag
    if (tid == 0) {
      unsigned fv = (unsigned)(t + 1);
      asm volatile("global_store_dword %0, %1, off sc0 sc1"
                   :: "v"(myfl), "v"(fv) : "memory");
    }
  }

  // ---- final GEMM: out = h_T @ Wo^T + Wo_b (blocks p<2 cover 512x256, fp32)
  if (p >= 2) return;
  {
    poll1(wvfl, (unsigned)T_);
    const unsigned char* ab =
        (const unsigned char*)hbuf + (size_t)((T_ - 1) & 1) * (HB * 2) + afr_b;
    u32x4 a0, a1, a2, a3;
    asm volatile("global_load_dwordx4 %0, %1, off sc0 sc1" : "=v"(a0) : "v"(ab) : "memory");
    asm volatile("global_load_dwordx4 %0, %1, off sc0 sc1" : "=v"(a1) : "v"(ab + 64) : "memory");
    asm volatile("global_load_dwordx4 %0, %1, off sc0 sc1" : "=v"(a2) : "v"(ab + 128) : "memory");
    asm volatile("global_load_dwordx4 %0, %1, off sc0 sc1" : "=v"(a3) : "v"(ab + 192) : "memory");
    asm volatile("s_waitcnt vmcnt(0)" ::: "memory");
    __builtin_amdgcn_sched_barrier(0);
    f32x4 acc[8];
#pragma unroll
    for (int nn = 0; nn < 8; ++nn) acc[nn] = (f32x4){0.f, 0.f, 0.f, 0.f};
    union { u32x4 u; bf16x8 v; } af;
#define RNN_OMF(KS, AV)                                                          \
    af.u = AV;                                                                   \
    _Pragma("unroll")                                                            \
    for (int nn = 0; nn < 8; ++nn) {                                             \
      bf16x8 b = cvt8(Wo_w + (size_t)(C0 + nn * 16 + l15) * H_ +                 \
                      wv * 128 + (KS) * 32 + k4 * 8);                            \
      acc[nn] = __builtin_amdgcn_mfma_f32_16x16x32_bf16(af.v, b, acc[nn], 0, 0, 0); \
    }
    RNN_OMF(0, a0) RNN_OMF(1, a1) RNN_OMF(2, a2) RNN_OMF(3, a3)
#undef RNN_OMF
#pragma unroll
    for (int nn = 0; nn < 8; ++nn)
#pragma unroll
      for (int r = 0; r < 4; ++r)
        red[wv][k4 * 4 + r][nn * 16 + l15] = acc[nn][r];
    __syncthreads();
    {
      f32x4 v = *reinterpret_cast<const f32x4*>(&red[0][erow][ec]);
#pragma unroll
      for (int s = 1; s < 8; ++s)
        v += *reinterpret_cast<const f32x4*>(&red[s][erow][ec]);
      v += *reinterpret_cast<const f32x4*>(Wo_b + C0 + ec);
      *reinterpret_cast<f32x4*>(out + (size_t)(R0 + erow) * O_ + C0 + ec) = v;
    }
  }
}

// ---------------------------------------------------------------------------
extern "C" void kernel_launch(void* const* d_in, const int* in_sizes, int n_in,
                              void* d_out, int out_size, void* d_ws, size_t ws_size,
                              hipStream_t stream) {
  const float* seq  = (const float*)d_in[0];
  const float* Wh_w = (const float*)d_in[1];
  const float* Wh_b = (const float*)d_in[2];
  const float* Wi_w = (const float*)d_in[3];
  const float* Wi_b = (const float*)d_in[4];
  const float* Wo_w = (const float*)d_in[5];
  const float* Wo_b = (const float*)d_in[6];

  char* ws = (char*)d_ws;
  unsigned short* hbuf   = (unsigned short*)ws; ws += (size_t)2 * HB * 2;  // 2 MB
  unsigned*       flags  = (unsigned*)ws;       ws += 32768;               // 32x8x128B
  unsigned short* seq_bf = (unsigned short*)ws;                            // 32 MB

  prep_kernel<<<2048, 256, 0, stream>>>(seq, seq_bf, flags);
  rnn_fused<<<256, 512, 0, stream>>>(seq_bf, Wh_w, Wh_b, Wi_w, Wi_b, Wo_w, Wo_b,
                                     hbuf, flags, (float*)d_out);
}